// Round 1
// baseline (274.508 us; speedup 1.0000x reference)
//
#include <hip/hip_runtime.h>

#define KI 32
#define BG_SAMPLE 100

// ws float layout:
//   per batch b: acc[224] = { cntk[32], cnt[32], sums[32*4], valsum[32] }   at b*224
//   mean[B][32*4]                                                           at B*224 + b*128
//   misc[B][4] = { sum_pair, l_reg, sum_bg, pad }                           at B*224+B*128 + b*4
// total = B*356 floats

static __device__ __forceinline__ float waveReduceSum(float v) {
#pragma unroll
  for (int off = 32; off > 0; off >>= 1) v += __shfl_down(v, off, 64);
  return v;
}

__global__ __launch_bounds__(256)
void pass1_kernel(const float* __restrict__ emb, const int* __restrict__ inst,
                  const float* __restrict__ kern, const float* __restrict__ tmask,
                  float* __restrict__ ws, int N, int bpb)
{
  const int b = blockIdx.y;
  __shared__ float acc[4][192];   // per-wave copies: cntk[32], cnt[32], sums[128]
  for (int i = threadIdx.x; i < 4 * 192; i += 256) (&acc[0][0])[i] = 0.f;
  __syncthreads();
  const int wave = threadIdx.x >> 6;
  const float* embb = emb + (size_t)b * 4 * N;
  const int*   instb = inst + (size_t)b * N;
  const float* kernb = kern + (size_t)b * N;
  const float* tmb   = tmask + (size_t)b * N;
  const int stride = bpb * 256;
  for (int i = blockIdx.x * 256 + threadIdx.x; i < N; i += stride) {
    int lab = instb[i];
    if (lab == 0) continue;            // segment 0 is excluded everywhere
    if (tmb[i] <= 0.5f) continue;      // masked -> label 0 -> excluded
    atomicAdd(&acc[wave][32 + lab], 1.0f);          // cnt (all pixels of label)
    if (kernb[i] > 0.5f) {                          // kernel-region stats
      atomicAdd(&acc[wave][lab], 1.0f);             // cnt_k
      float e0 = embb[i];
      float e1 = embb[(size_t)N + i];
      float e2 = embb[(size_t)2 * N + i];
      float e3 = embb[(size_t)3 * N + i];
      atomicAdd(&acc[wave][64 + lab * 4 + 0], e0);
      atomicAdd(&acc[wave][64 + lab * 4 + 1], e1);
      atomicAdd(&acc[wave][64 + lab * 4 + 2], e2);
      atomicAdd(&acc[wave][64 + lab * 4 + 3], e3);
    }
  }
  __syncthreads();
  float* gacc = ws + (size_t)b * 224;
  for (int i = threadIdx.x; i < 192; i += 256) {
    float v = acc[0][i] + acc[1][i] + acc[2][i] + acc[3][i];
    if (v != 0.f) atomicAdd(&gacc[i], v);
  }
}

__global__ __launch_bounds__(256)
void stats_kernel(float* __restrict__ ws, int B)
{
  const int b = blockIdx.x;
  float* gacc  = ws + (size_t)b * 224;
  float* gmean = ws + (size_t)B * 224 + (size_t)b * 128;
  float* gmisc = ws + (size_t)B * 224 + (size_t)B * 128 + (size_t)b * 4;
  __shared__ float mean[KI][4];
  const int t = threadIdx.x;
  if (t < KI) {
    float inv = (t == 0) ? 0.f : 1.0f / fmaxf(gacc[t], 1.0f);
#pragma unroll
    for (int d = 0; d < 4; ++d) {
      float m = gacc[64 + t * 4 + d] * inv;
      mean[t][d] = m;
      gmean[t * 4 + d] = m;
    }
  }
  __syncthreads();
  const float coef = 1.0f - expf(-10.0f / 32.0f);
  float lp = 0.f;
  for (int idx = t; idx < 31 * 31; idx += 256) {
    int i = 1 + idx / 31, j = 1 + idx % 31;
    if (i == j) continue;
    float d0 = mean[i][0] - mean[j][0];
    float d1 = mean[i][1] - mean[j][1];
    float d2 = mean[i][2] - mean[j][2];
    float d3 = mean[i][3] - mean[j][3];
    float pd = sqrtf(d0 * d0 + d1 * d1 + d2 * d2 + d3 * d3);
    float a = fmaxf(3.0f - coef * pd, 0.f);
    lp += logf(a * a + 1.f);
  }
  float lr = 0.f;
  for (int k = t; k < KI; k += 256) {
    float n = sqrtf(mean[k][0] * mean[k][0] + mean[k][1] * mean[k][1] +
                    mean[k][2] * mean[k][2] + mean[k][3] * mean[k][3]);
    lr += logf(n + 1.f);
  }
  float spw = waveReduceSum(lp);
  float lrw = waveReduceSum(lr);
  __shared__ float red[2][4];
  if ((t & 63) == 0) { red[0][t >> 6] = spw; red[1][t >> 6] = lrw; }
  __syncthreads();
  if (t == 0) {
    gmisc[0] = red[0][0] + red[0][1] + red[0][2] + red[0][3];
    gmisc[1] = (red[1][0] + red[1][1] + red[1][2] + red[1][3]) * (0.001f / 32.0f);
  }
}

__global__ __launch_bounds__(256)
void bg_kernel(const float* __restrict__ emb, const int* __restrict__ inst,
               const float* __restrict__ tmask, float* __restrict__ ws, int N, int B)
{
  const int b = blockIdx.x;
  const int t = threadIdx.x;
  const int lane = t & 63, wave = t >> 6;
  __shared__ int s_bgidx[BG_SAMPLE];
  __shared__ int s_count;
  __shared__ int s_wcnt[4];
  if (t == 0) s_count = 0;
  __syncthreads();
  const int*   instb = inst + (size_t)b * N;
  const float* tmb   = tmask + (size_t)b * N;

  for (int base = 0; base < N; base += 256) {
    if (s_count >= BG_SAMPLE) break;
    int i = base + t;
    bool p = false;
    if (i < N) {
      int lab = instb[i];
      if (tmb[i] <= 0.5f) lab = 0;
      p = (lab == 0);
    }
    unsigned long long m = __ballot(p);
    if (lane == 0) s_wcnt[wave] = __popcll(m);
    __syncthreads();
    int pos = s_count;
    for (int w = 0; w < wave; ++w) pos += s_wcnt[w];
    if (p) {
      pos += __popcll(m & ((1ull << lane) - 1ull));
      if (pos < BG_SAMPLE) s_bgidx[pos] = i;
    }
    __syncthreads();
    if (t == 0) s_count += s_wcnt[0] + s_wcnt[1] + s_wcnt[2] + s_wcnt[3];
    __syncthreads();
  }
  // fallback (stable-argsort semantics): if < 100 background pixels, the
  // remaining slots are the first non-background indices.
  if (s_count < BG_SAMPLE) {
    for (int base = 0; base < N; base += 256) {
      if (s_count >= BG_SAMPLE) break;
      int i = base + t;
      bool p = false;
      if (i < N) {
        int lab = instb[i];
        if (tmb[i] <= 0.5f) lab = 0;
        p = (lab != 0);
      }
      unsigned long long m = __ballot(p);
      if (lane == 0) s_wcnt[wave] = __popcll(m);
      __syncthreads();
      int pos = s_count;
      for (int w = 0; w < wave; ++w) pos += s_wcnt[w];
      if (p) {
        pos += __popcll(m & ((1ull << lane) - 1ull));
        if (pos < BG_SAMPLE) s_bgidx[pos] = i;
      }
      __syncthreads();
      if (t == 0) s_count += s_wcnt[0] + s_wcnt[1] + s_wcnt[2] + s_wcnt[3];
      __syncthreads();
    }
  }
  __syncthreads();

  __shared__ float ebg[BG_SAMPLE][4];
  const float* embb = emb + (size_t)b * 4 * N;
  for (int j = t; j < BG_SAMPLE; j += 256) {
    int i = s_bgidx[j];
    ebg[j][0] = embb[i];
    ebg[j][1] = embb[(size_t)N + i];
    ebg[j][2] = embb[(size_t)2 * N + i];
    ebg[j][3] = embb[(size_t)3 * N + i];
  }
  __shared__ float mean[KI][4];
  float* gmean = ws + (size_t)B * 224 + (size_t)b * 128;
  if (t < 128) (&mean[0][0])[t] = gmean[t];
  __syncthreads();

  const float coef = 1.0f - expf(-10.0f / 32.0f);
  float local = 0.f;
  for (int idx = t; idx < 31 * BG_SAMPLE; idx += 256) {
    int k = 1 + idx / BG_SAMPLE, j = idx % BG_SAMPLE;
    float d0 = ebg[j][0] - mean[k][0];
    float d1 = ebg[j][1] - mean[k][1];
    float d2 = ebg[j][2] - mean[k][2];
    float d3 = ebg[j][3] - mean[k][3];
    float dd = sqrtf(d0 * d0 + d1 * d1 + d2 * d2 + d3 * d3);
    float a = fmaxf(3.0f - coef * dd, 0.f);
    local += logf(a * a + 1.f);
  }
  float w = waveReduceSum(local);
  __shared__ float red[4];
  if (lane == 0) red[wave] = w;
  __syncthreads();
  if (t == 0) {
    float* gmisc = ws + (size_t)B * 224 + (size_t)B * 128 + (size_t)b * 4;
    gmisc[2] = (red[0] + red[1] + red[2] + red[3]) * (1.0f / BG_SAMPLE);
  }
}

__global__ __launch_bounds__(256)
void pass2_kernel(const float* __restrict__ emb, const int* __restrict__ inst,
                  const float* __restrict__ tmask, const float* __restrict__ maxd,
                  float* __restrict__ ws, int N, int B, int bpb)
{
  const int b = blockIdx.y;
  const int t = threadIdx.x;
  __shared__ float mean[KI][4];
  __shared__ float scal[KI];
  __shared__ float vacc[4][KI];
  float* gmean = ws + (size_t)B * 224 + (size_t)b * 128;
  if (t < 128) (&mean[0][0])[t] = gmean[t];
  if (t < KI) scal[t] = expf(maxd[b * KI + t]);
  for (int i = t; i < 4 * KI; i += 256) (&vacc[0][0])[i] = 0.f;
  __syncthreads();
  const float* embb = emb + (size_t)b * 4 * N;
  const int*   instb = inst + (size_t)b * N;
  const float* tmb   = tmask + (size_t)b * N;
  const int wave = t >> 6;
  const int stride = bpb * 256;
  for (int i = blockIdx.x * 256 + t; i < N; i += stride) {
    int lab = instb[i];
    if (lab == 0) continue;
    if (tmb[i] <= 0.5f) continue;
    float d0 = embb[i]               - mean[lab][0];
    float d1 = embb[(size_t)N + i]   - mean[lab][1];
    float d2 = embb[(size_t)2*N + i] - mean[lab][2];
    float d3 = embb[(size_t)3*N + i] - mean[lab][3];
    float d = sqrtf(d0 * d0 + d1 * d1 + d2 * d2 + d3 * d3);
    float a = fmaxf(scal[lab] * d - 0.5f, 0.f);
    atomicAdd(&vacc[wave][lab], logf(a * a + 1.f));
  }
  __syncthreads();
  float* gval = ws + (size_t)b * 224 + 192;
  for (int i = t; i < KI; i += 256) {
    float v = vacc[0][i] + vacc[1][i] + vacc[2][i] + vacc[3][i];
    if (v != 0.f) atomicAdd(&gval[i], v);
  }
}

__global__ __launch_bounds__(64)
void final_kernel(const float* __restrict__ ws, float* __restrict__ out, int B)
{
  const int t = threadIdx.x;
  __shared__ float s[64];
  float tot = 0.f;
  if (t < B) {
    const float* gacc  = ws + (size_t)t * 224;
    const float* gmisc = ws + (size_t)B * 224 + (size_t)B * 128 + (size_t)t * 4;
    float lagg = 0.f;
    for (int k = 1; k < KI; ++k)
      lagg += gacc[192 + k] / fmaxf(gacc[32 + k], 1.0f);
    lagg *= (1.0f / 31.0f);
    float ldis = (gmisc[0] + gmisc[2]) * (1.0f / 961.0f);  // (K-1)(K-2)+(K-1)
    tot = lagg + ldis + gmisc[1];
  }
  s[t] = tot;
  __syncthreads();
  if (t == 0) {
    float sum = 0.f;
    for (int b = 0; b < B; ++b) sum += s[b];
    out[0] = sum / (float)B;
  }
}

extern "C" void kernel_launch(void* const* d_in, const int* in_sizes, int n_in,
                              void* d_out, int out_size, void* d_ws, size_t ws_size,
                              hipStream_t stream)
{
  const float* emb   = (const float*)d_in[0];
  const int*   inst  = (const int*)d_in[1];
  const float* kern  = (const float*)d_in[2];
  const float* tmask = (const float*)d_in[3];
  const float* maxd  = (const float*)d_in[5];
  float* out = (float*)d_out;
  float* ws  = (float*)d_ws;

  const int B = in_sizes[5] / KI;          // 16
  const int N = in_sizes[1] / B;           // 409600
  const int bpb = 128;

  if (ws_size < (size_t)B * 356 * sizeof(float)) return;

  hipMemsetAsync(d_ws, 0, (size_t)B * 356 * sizeof(float), stream);
  pass1_kernel<<<dim3(bpb, B), 256, 0, stream>>>(emb, inst, kern, tmask, ws, N, bpb);
  stats_kernel<<<B, 256, 0, stream>>>(ws, B);
  bg_kernel<<<B, 256, 0, stream>>>(emb, inst, tmask, ws, N, B);
  pass2_kernel<<<dim3(bpb, B), 256, 0, stream>>>(emb, inst, tmask, maxd, ws, N, B, bpb);
  final_kernel<<<1, 64, 0, stream>>>(ws, out, B);
}